// Round 1
// baseline (529.555 us; speedup 1.0000x reference)
//
#include <hip/hip_runtime.h>

// Output: (1, 8, 4096, 4096) float32, 512 MiB. Pure write-BW bound.
//   plane c in [0,4):  out[c,i,j] = table[seq[i]*4 + c]      -> constant per row
//   plane c in [4,8):  out[c,i,j] = table[seq[j]*4 + (c-4)]  -> identical row repeated over i
//
// Exploit the redundancy: each block owns (plane, 4-row chunk), computes its
// values ONCE into registers, then streams 16 contiguous NT float4 stores per
// thread with no loads in the inner loop.
//
// Grid: 8 planes x 1024 chunks = 8192 blocks x 256 threads.
// Per block: 4 rows x 16 KiB = 64 KiB written; 16 f4 stores/thread.

#define L 4096
#define ROWS 4                      // rows per block
#define ROW_F4 (L / 4)              // 1024 float4 per row
#define PLANE_F4 (L * (L / 4))      // 4,194,304 float4 per plane

typedef float v4f __attribute__((ext_vector_type(4)));
typedef int   v4i __attribute__((ext_vector_type(4)));

__global__ __launch_bounds__(256) void SequenceEmbedding_30923764532139_kernel(
        const int* __restrict__ seq,
        const float* __restrict__ table,
        v4f* __restrict__ out) {
    const unsigned bid   = blockIdx.x;
    const unsigned plane = bid >> 10;            // 0..7  (wave-uniform)
    const unsigned i0    = (bid & 1023u) * ROWS; // first row of this chunk
    const unsigned t     = threadIdx.x;          // 0..255

    v4f* base = out + (size_t)plane * PLANE_F4 + (size_t)i0 * ROW_F4;

    if (plane < 4u) {
        // Row-constant planes: one table value per row, broadcast along j.
        const unsigned c = plane;
        float x[ROWS];
#pragma unroll
        for (int r = 0; r < ROWS; ++r)
            x[r] = table[(unsigned)seq[i0 + r] * 4u + c];

#pragma unroll
        for (int r = 0; r < ROWS; ++r) {
            const v4f val = (v4f){x[r], x[r], x[r], x[r]};
            v4f* rowp = base + (size_t)r * ROW_F4;
#pragma unroll
            for (int k = 0; k < 4; ++k)
                __builtin_nontemporal_store(val, rowp + (unsigned)k * 256u + t);
        }
    } else {
        // Column-pattern planes: the row vector depends only on j; compute the
        // thread's 4 float4 slices once, then replay them for every row.
        const unsigned cc = plane - 4u;
        v4f vals[4];
#pragma unroll
        for (int k = 0; k < 4; ++k) {
            const unsigned j = (unsigned)k * 1024u + t * 4u;   // float index
            const v4i s = *(const v4i*)(seq + j);              // 16B aligned
            vals[k].x = table[(unsigned)s.x * 4u + cc];
            vals[k].y = table[(unsigned)s.y * 4u + cc];
            vals[k].z = table[(unsigned)s.z * 4u + cc];
            vals[k].w = table[(unsigned)s.w * 4u + cc];
        }

#pragma unroll
        for (int r = 0; r < ROWS; ++r) {
            v4f* rowp = base + (size_t)r * ROW_F4;
#pragma unroll
            for (int k = 0; k < 4; ++k)
                __builtin_nontemporal_store(vals[k], rowp + (unsigned)k * 256u + t);
        }
    }
}

extern "C" void kernel_launch(void* const* d_in, const int* in_sizes, int n_in,
                              void* d_out, int out_size, void* d_ws, size_t ws_size,
                              hipStream_t stream) {
    const int*   seq   = (const int*)d_in[0];
    const float* table = (const float*)d_in[1];
    v4f*         out   = (v4f*)d_out;

    dim3 block(256);
    dim3 grid(8u * (L / ROWS));   // 8192 blocks, exact cover
    SequenceEmbedding_30923764532139_kernel<<<grid, block, 0, stream>>>(seq, table, out);
}

// Round 2
// 525.148 us; speedup vs baseline: 1.0084x; 1.0084x over previous
//
#include <hip/hip_runtime.h>

// Output: (1, 8, 4096, 4096) float32, 512 MiB. Pure write-BW bound.
//   plane c in [0,4):  out[c,i,j] = table[seq[i]*4 + c]      -> constant per row
//   plane c in [4,8):  out[c,i,j] = table[seq[j]*4 + (c-4)]  -> identical row repeated over i
//
// Round-1 lesson: restructuring (16 stores/thread, no inner-loop loads) was
// NEUTRAL vs one-store-per-thread -> not launch/latency/issue bound. Kernel
// sustains only ~3 TB/s while the harness memset hits 6.3 TB/s with PLAIN
// stores. This round: identical structure, NT stores -> plain stores (let L2
// write-combine + evict as full streams, like memset does).
//
// Grid: 8 planes x 1024 chunks = 8192 blocks x 256 threads.
// Per block: 4 rows x 16 KiB = 64 KiB written; 16 f4 stores/thread.

#define L 4096
#define ROWS 4                      // rows per block
#define ROW_F4 (L / 4)              // 1024 float4 per row
#define PLANE_F4 (L * (L / 4))      // 4,194,304 float4 per plane

typedef float v4f __attribute__((ext_vector_type(4)));
typedef int   v4i __attribute__((ext_vector_type(4)));

__global__ __launch_bounds__(256) void SequenceEmbedding_30923764532139_kernel(
        const int* __restrict__ seq,
        const float* __restrict__ table,
        v4f* __restrict__ out) {
    const unsigned bid   = blockIdx.x;
    const unsigned plane = bid >> 10;            // 0..7  (wave-uniform)
    const unsigned i0    = (bid & 1023u) * ROWS; // first row of this chunk
    const unsigned t     = threadIdx.x;          // 0..255

    v4f* base = out + (size_t)plane * PLANE_F4 + (size_t)i0 * ROW_F4;

    if (plane < 4u) {
        // Row-constant planes: one table value per row, broadcast along j.
        const unsigned c = plane;
        float x[ROWS];
#pragma unroll
        for (int r = 0; r < ROWS; ++r)
            x[r] = table[(unsigned)seq[i0 + r] * 4u + c];

#pragma unroll
        for (int r = 0; r < ROWS; ++r) {
            const v4f val = (v4f){x[r], x[r], x[r], x[r]};
            v4f* rowp = base + (size_t)r * ROW_F4;
#pragma unroll
            for (int k = 0; k < 4; ++k)
                rowp[(unsigned)k * 256u + t] = val;          // plain store
        }
    } else {
        // Column-pattern planes: the row vector depends only on j; compute the
        // thread's 4 float4 slices once, then replay them for every row.
        const unsigned cc = plane - 4u;
        v4f vals[4];
#pragma unroll
        for (int k = 0; k < 4; ++k) {
            const unsigned j = (unsigned)k * 1024u + t * 4u;   // float index
            const v4i s = *(const v4i*)(seq + j);              // 16B aligned
            vals[k].x = table[(unsigned)s.x * 4u + cc];
            vals[k].y = table[(unsigned)s.y * 4u + cc];
            vals[k].z = table[(unsigned)s.z * 4u + cc];
            vals[k].w = table[(unsigned)s.w * 4u + cc];
        }

#pragma unroll
        for (int r = 0; r < ROWS; ++r) {
            v4f* rowp = base + (size_t)r * ROW_F4;
#pragma unroll
            for (int k = 0; k < 4; ++k)
                rowp[(unsigned)k * 256u + t] = vals[k];      // plain store
        }
    }
}

extern "C" void kernel_launch(void* const* d_in, const int* in_sizes, int n_in,
                              void* d_out, int out_size, void* d_ws, size_t ws_size,
                              hipStream_t stream) {
    const int*   seq   = (const int*)d_in[0];
    const float* table = (const float*)d_in[1];
    v4f*         out   = (v4f*)d_out;

    dim3 block(256);
    dim3 grid(8u * (L / ROWS));   // 8192 blocks, exact cover
    SequenceEmbedding_30923764532139_kernel<<<grid, block, 0, stream>>>(seq, table, out);
}